// Round 7
// baseline (342.438 us; speedup 1.0000x reference)
//
#include <hip/hip_runtime.h>

namespace {

constexpr int NB = 4;
constexpr int NC = 256;   // C == HID
constexpr int NN = 4096;  // 64*64

typedef __attribute__((ext_vector_type(8))) short bf8;
typedef __attribute__((ext_vector_type(4))) float f4;
typedef unsigned short ushort_t;
typedef unsigned long long ull;

__device__ __forceinline__ float bf2f(unsigned short u) {
  return __uint_as_float(((unsigned)u) << 16);
}
__device__ __forceinline__ unsigned short f2bf(float f) {  // RNE
  unsigned x = __float_as_uint(f);
  return (unsigned short)((x + 0x7FFFu + ((x >> 16) & 1u)) >> 16);
}
__device__ __forceinline__ unsigned enc_f(float f) {
  unsigned u = __float_as_uint(f);
  return (u & 0x80000000u) ? ~u : (u | 0x80000000u);  // monotonic float->uint
}
__device__ __forceinline__ float dec_e(unsigned e) {   // inverse of enc_f
  return __uint_as_float((e & 0x80000000u) ? (e ^ 0x80000000u) : ~e);
}

// sorted-descending 8-element insert (keys pack (val asc-enc, ~idx))
__device__ __forceinline__ void ins8(ull* b, ull k) {
  if (k <= b[7]) return;
  b[7] = k;
#pragma unroll
  for (int p = 7; p >= 1; --p) {
    if (b[p] > b[p-1]) { ull t = b[p]; b[p] = b[p-1]; b[p-1] = t; }
  }
}

__device__ __forceinline__ ull shfl_xor_ull(ull v, int mask) {
  unsigned lo = (unsigned)(v & 0xFFFFFFFFull), hi = (unsigned)(v >> 32);
  lo = (unsigned)__shfl_xor((int)lo, mask);
  hi = (unsigned)__shfl_xor((int)hi, mask);
  return ((ull)hi << 32) | (ull)lo;
}

// merge partner lists via shfl butterfly (levels 1..maxs), snapshot-then-insert
template<int MAXS>
__device__ __forceinline__ void shfl_merge8(ull* b) {
#pragma unroll
  for (int s = 1; s <= MAXS; s <<= 1) {
    ull tmp[8];
#pragma unroll
    for (int k = 0; k < 8; ++k) tmp[k] = shfl_xor_ull(b[k], s);
#pragma unroll
    for (int k = 0; k < 8; ++k) ins8(b, tmp[k]);
  }
}

// ---------- 1. inverse row norms of batch-0 features (+ zero counts/bnsum) ----------
__global__ __launch_bounds__(256) void norm_kernel(const float* __restrict__ feat,
                                                   float* __restrict__ inv,
                                                   int* __restrict__ counts,
                                                   float* __restrict__ bnsum) {
  int n = blockIdx.x * 256 + threadIdx.x;
  counts[n] = 0;
  if (n < 2 * NC) bnsum[n] = 0.f;
  float ss = 0.f;
  for (int c = 0; c < NC; ++c) { float v = feat[(size_t)c * NN + n]; ss = fmaf(v, v, ss); }
  inv[n] = 1.f / fmaxf(sqrtf(ss), 1e-12f);
}

// ---------- 2. feat [B][C][N] -> xin [B*N][C] bf16 ; b==0 also emits Xhi/Xlo ----------
__global__ __launch_bounds__(256) void feat2bf_kernel(const float* __restrict__ feat,
                                                      const float* __restrict__ inv,
                                                      unsigned short* __restrict__ xin,
                                                      unsigned short* __restrict__ Xhi,
                                                      unsigned short* __restrict__ Xlo) {
  __shared__ float tile[64][65];
  int n0 = blockIdx.x * 64, c0 = blockIdx.y * 64, b = blockIdx.z;
  int tid = threadIdx.x;
#pragma unroll
  for (int i = 0; i < 4; ++i) {
    int u = tid + i * 256; int cr = u >> 4, q = u & 15;
    float4 v = *(const float4*)&feat[((size_t)b * NC + c0 + cr) * NN + n0 + q * 4];
    tile[cr][q*4+0] = v.x; tile[cr][q*4+1] = v.y; tile[cr][q*4+2] = v.z; tile[cr][q*4+3] = v.w;
  }
  __syncthreads();
#pragma unroll
  for (int i = 0; i < 4; ++i) {
    int u = tid + i * 256; int nr = u >> 4, q = u & 15;
    float x0 = tile[q*4+0][nr], x1 = tile[q*4+1][nr];
    float x2 = tile[q*4+2][nr], x3 = tile[q*4+3][nr];
    ushort4 o;
    o.x = f2bf(x0); o.y = f2bf(x1); o.z = f2bf(x2); o.w = f2bf(x3);
    *(ushort4*)&xin[((size_t)(b << 12) + n0 + nr) * NC + c0 + q * 4] = o;
    if (b == 0) {
      float iv = inv[n0 + nr];
      float y0 = x0 * iv, y1 = x1 * iv, y2 = x2 * iv, y3 = x3 * iv;
      ushort4 h, l;
      h.x = f2bf(y0); l.x = f2bf(y0 - bf2f(h.x));
      h.y = f2bf(y1); l.y = f2bf(y1 - bf2f(h.y));
      h.z = f2bf(y2); l.z = f2bf(y2 - bf2f(h.z));
      h.w = f2bf(y3); l.w = f2bf(y3 - bf2f(h.w));
      size_t oo = (size_t)(n0 + nr) * NC + c0 + q * 4;
      *(ushort4*)&Xhi[oo] = h;
      *(ushort4*)&Xlo[oo] = l;
    }
  }
}

// ---------- 3. weight convert: W[k][n] fp32 -> Wt[n][k] bf16 (5 matrices) ----------
__global__ __launch_bounds__(256) void wcvt_kernel(const float* __restrict__ w0,
                                                   const float* __restrict__ w1,
                                                   const float* __restrict__ w2,
                                                   const float* __restrict__ w3,
                                                   const float* __restrict__ w4,
                                                   unsigned short* __restrict__ Wt) {
  __shared__ float tile[64][65];
  int z = blockIdx.z;
  const float* W = (z == 0) ? w0 : (z == 1) ? w1 : (z == 2) ? w2 : (z == 3) ? w3 : w4;
  int k0 = blockIdx.x * 64, n0 = blockIdx.y * 64;
  int tid = threadIdx.x;
#pragma unroll
  for (int i = 0; i < 4; ++i) {
    int u = tid + i * 256; int kr = u >> 4, q = u & 15;
    float4 v = *(const float4*)&W[(size_t)(k0 + kr) * NC + n0 + q * 4];
    tile[kr][q*4+0] = v.x; tile[kr][q*4+1] = v.y; tile[kr][q*4+2] = v.z; tile[kr][q*4+3] = v.w;
  }
  __syncthreads();
#pragma unroll
  for (int i = 0; i < 4; ++i) {
    int u = tid + i * 256; int nr = u >> 4, q = u & 15;
    ushort4 o;
    o.x = f2bf(tile[q*4+0][nr]); o.y = f2bf(tile[q*4+1][nr]);
    o.z = f2bf(tile[q*4+2][nr]); o.w = f2bf(tile[q*4+3][nr]);
    *(ushort4*)&Wt[(size_t)z * 65536 + (size_t)(n0 + nr) * NC + k0 + q * 4] = o;
  }
}

// ---------- 4. symmetric fused sim (split-bf16 MFMA) + dual top-8 extraction ----------
// 528 upper-triangle 128x128 blocks. Staging/frag addresses fully precomputed (imm-folded
// k offsets); extraction float-screened (exact-conservative) before 64-bit ins8.
__global__ __launch_bounds__(512) void simtop_kernel(const unsigned short* __restrict__ Xhi,
                                                     const unsigned short* __restrict__ Xlo,
                                                     ull* __restrict__ cand) {
  __shared__ __align__(16) char lds[73728];
  // staging: 4 buffers of [128][72] shorts at offsets 0 / 18432 / 36864 / 55296
  float (*simT)[132] = (float(*)[132])(lds);   // 67584 B, aliases staging after compute

  int tid = threadIdx.x, wave = tid >> 6, lane = tid & 63;
  int wm = wave >> 2, wn = wave & 3;   // 2 x 4 waves, wave tile 64x32
  int orig = blockIdx.x;
  int bid = (orig & 7) * 66 + (orig >> 3);  // XCD-chunked bijection (528 = 8*66)
  int pi = (int)((sqrtf(8.f * (float)bid + 1.f) - 1.f) * 0.5f);
  while ((pi + 1) * (pi + 2) / 2 <= bid) ++pi;
  while (pi * (pi + 1) / 2 > bid) --pi;
  int pj = bid - pi * (pi + 1) / 2;
  int m0 = pj * 128, n0 = pi * 128;

  // staging thread map: row sr, q-slots (q0, q0+1); all per-k addresses imm-folded
  int sr = tid >> 2;
  int q0 = (tid & 3) * 2;
  int s_ = (sr >> 1) & 7;
  int qp0 = q0 ^ s_;
  const ushort_t* gAh = Xhi + (size_t)(m0 + sr) * NC + q0 * 8;
  const ushort_t* gAl = Xlo + (size_t)(m0 + sr) * NC + q0 * 8;
  const ushort_t* gBh = Xhi + (size_t)(n0 + sr) * NC + q0 * 8;
  const ushort_t* gBl = Xlo + (size_t)(n0 + sr) * NC + q0 * 8;
  int d0 = sr * 144 + qp0 * 16;            // LDS byte offset for slot q0
  int d1 = sr * 144 + (qp0 ^ 1) * 16;      // slot q0+1 -> swizzled qp0^1 (NOT d0^16: 144 has bit4)

  // frag-read LDS byte offsets (constant across k-steps)
  int oA[2][4], oB[2][2];
#pragma unroll
  for (int ks = 0; ks < 2; ++ks) {
    int qr = ks * 4 + (lane >> 4);
#pragma unroll
    for (int mf = 0; mf < 4; ++mf) {
      int rr = wm * 64 + mf * 16 + (lane & 15);
      oA[ks][mf] = rr * 144 + (qr ^ ((rr >> 1) & 7)) * 16;
    }
#pragma unroll
    for (int nf = 0; nf < 2; ++nf) {
      int rr = wn * 32 + nf * 16 + (lane & 15);
      oB[ks][nf] = rr * 144 + (qr ^ ((rr >> 1) & 7)) * 16;
    }
  }

  f4 acc[4][2];
#pragma unroll
  for (int i = 0; i < 4; ++i)
#pragma unroll
    for (int j = 0; j < 2; ++j) acc[i][j] = (f4){0.f, 0.f, 0.f, 0.f};

#pragma unroll
  for (int kk = 0; kk < 4; ++kk) {
    {
      uint4 a0 = *(const uint4*)(gAh + kk * 64);
      uint4 a1 = *(const uint4*)(gAh + kk * 64 + 8);
      uint4 a2 = *(const uint4*)(gAl + kk * 64);
      uint4 a3 = *(const uint4*)(gAl + kk * 64 + 8);
      uint4 b0 = *(const uint4*)(gBh + kk * 64);
      uint4 b1 = *(const uint4*)(gBh + kk * 64 + 8);
      uint4 b2 = *(const uint4*)(gBl + kk * 64);
      uint4 b3 = *(const uint4*)(gBl + kk * 64 + 8);
      *(uint4*)(lds +         d0) = a0;  *(uint4*)(lds +         d1) = a1;
      *(uint4*)(lds + 18432 + d0) = a2;  *(uint4*)(lds + 18432 + d1) = a3;
      *(uint4*)(lds + 36864 + d0) = b0;  *(uint4*)(lds + 36864 + d1) = b1;
      *(uint4*)(lds + 55296 + d0) = b2;  *(uint4*)(lds + 55296 + d1) = b3;
    }
    __syncthreads();
#pragma unroll
    for (int ks = 0; ks < 2; ++ks) {
      bf8 ah[4], al[4], bh[2], bl[2];
#pragma unroll
      for (int mf = 0; mf < 4; ++mf) {
        ah[mf] = *(const bf8*)(lds +         oA[ks][mf]);
        al[mf] = *(const bf8*)(lds + 18432 + oA[ks][mf]);
      }
#pragma unroll
      for (int nf = 0; nf < 2; ++nf) {
        bh[nf] = *(const bf8*)(lds + 36864 + oB[ks][nf]);
        bl[nf] = *(const bf8*)(lds + 55296 + oB[ks][nf]);
      }
#pragma unroll
      for (int nf = 0; nf < 2; ++nf)
#pragma unroll
        for (int mf = 0; mf < 4; ++mf) {
          acc[mf][nf] = __builtin_amdgcn_mfma_f32_16x16x32_bf16(ah[mf], bh[nf], acc[mf][nf], 0, 0, 0);
          acc[mf][nf] = __builtin_amdgcn_mfma_f32_16x16x32_bf16(ah[mf], bl[nf], acc[mf][nf], 0, 0, 0);
          acc[mf][nf] = __builtin_amdgcn_mfma_f32_16x16x32_bf16(al[mf], bh[nf], acc[mf][nf], 0, 0, 0);
        }
    }
    __syncthreads();
  }

  // spill acc -> simT fp32 tile
#pragma unroll
  for (int mf = 0; mf < 4; ++mf)
#pragma unroll
    for (int nf = 0; nf < 2; ++nf) {
      int cl = wn * 32 + nf * 16 + (lane & 15);
      int rbase = wm * 64 + mf * 16 + (lane >> 4) * 4;
#pragma unroll
      for (int r = 0; r < 4; ++r)
        simT[rbase + r][cl] = acc[mf][nf][r];
    }
  __syncthreads();

  // row extraction: 4 threads/row, float4 group-screen then exact ins8
  {
    int rl = tid >> 2, q4 = tid & 3;
    const float* rowp = &simT[rl][q4 * 32];
    ull b8[8] = {0,0,0,0,0,0,0,0};
    float thr = -3.0e38f;
#pragma unroll
    for (int i = 0; i < 8; ++i) {
      int off = ((i + q4 * 2) & 7) * 4;
      float4 v = *(const float4*)(rowp + off);
      if (fmaxf(fmaxf(v.x, v.y), fmaxf(v.z, v.w)) >= thr) {
        int jb = n0 + q4 * 32 + off;
        ins8(b8, ((ull)enc_f(v.x) << 32) | (ull)(0xFFFFFFFFu - (unsigned)(jb + 0)));
        ins8(b8, ((ull)enc_f(v.y) << 32) | (ull)(0xFFFFFFFFu - (unsigned)(jb + 1)));
        ins8(b8, ((ull)enc_f(v.z) << 32) | (ull)(0xFFFFFFFFu - (unsigned)(jb + 2)));
        ins8(b8, ((ull)enc_f(v.w) << 32) | (ull)(0xFFFFFFFFu - (unsigned)(jb + 3)));
        unsigned h = (unsigned)(b8[7] >> 32);
        thr = h ? dec_e(h) : -3.0e38f;
      }
    }
    shfl_merge8<2>(b8);
    if (q4 == 0) {
      ull* dst = cand + (size_t)(m0 + rl) * 256 + pi * 8;
#pragma unroll
      for (int k = 0; k < 8; ++k) dst[k] = b8[k];
    }
  }

  // column extraction (transposed candidates) for off-diagonal blocks
  if (pi != pj) {
    int ccol = tid >> 2, seg = tid & 3;
    ull c8[8] = {0,0,0,0,0,0,0,0};
    float thr = -3.0e38f;
    for (int i = 0; i < 32; ++i) {
      int rr = seg * 32 + ((i + seg) & 31);
      float v = simT[rr][ccol];
      if (v >= thr) {
        ins8(c8, ((ull)enc_f(v) << 32) | (ull)(0xFFFFFFFFu - (unsigned)(m0 + rr)));
        unsigned h = (unsigned)(c8[7] >> 32);
        thr = h ? dec_e(h) : -3.0e38f;
      }
    }
    shfl_merge8<2>(c8);
    if (seg == 0) {
      ull* dst = cand + (size_t)(n0 + ccol) * 256 + pj * 8;
#pragma unroll
      for (int k = 0; k < 8; ++k) dst[k] = c8[k];
    }
  }
}

// ---------- 5. merge per-tile candidates -> exact global top-8 (+ counts) ----------
__global__ __launch_bounds__(256) void merge_kernel(const ull* __restrict__ cand,
                                                    int* __restrict__ idx8,
                                                    int* __restrict__ counts) {
  int t = blockIdx.x * 256 + threadIdx.x;   // 32768 = 4096 rows x 8
  int row = t >> 3, part = t & 7;
  const ull* cp = cand + (size_t)row * 256 + part * 32;
  ull b8[8] = {0,0,0,0,0,0,0,0};
  for (int g = 0; g < 4; ++g) {
#pragma unroll 1
    for (int k = 0; k < 8; ++k) {
      ull key = cp[g * 8 + k];
      if (key <= b8[7]) break;
      ins8(b8, key);
    }
  }
  shfl_merge8<4>(b8);
  if (part == 0) {
#pragma unroll
    for (int k = 0; k < 8; ++k) {
      int j = (int)(0xFFFFFFFFu - (unsigned)(b8[k] & 0xFFFFFFFFull));
      idx8[row * 8 + k] = j;
      atomicAdd(&counts[j], 1);
    }
  }
}

// ---------- 6. CSR prefix scan (exclusive) + cursor init ----------
__global__ __launch_bounds__(256) void scan_kernel(const int* __restrict__ counts,
                                                   int* __restrict__ offsets,
                                                   int* __restrict__ cursor) {
  __shared__ int ssum[256];
  __shared__ int sbase[257];
  int t = threadIdx.x;
  int loc[16];
  int s = 0;
#pragma unroll
  for (int i = 0; i < 16; ++i) { loc[i] = s; s += counts[t*16 + i]; }
  ssum[t] = s;
  __syncthreads();
  if (t == 0) {
    int acc = 0;
    for (int i = 0; i < 256; ++i) { sbase[i] = acc; acc += ssum[i]; }
    sbase[256] = acc;
  }
  __syncthreads();
  int b0 = sbase[t];
#pragma unroll
  for (int i = 0; i < 16; ++i) {
    int off = b0 + loc[i];
    offsets[t*16 + i] = off;
    cursor [t*16 + i] = off;
  }
  if (t == 0) offsets[NN] = sbase[256];
}

// ---------- 7. CSR fill ----------
__global__ __launch_bounds__(256) void fill_kernel(const int* __restrict__ idx8,
                                                   int* __restrict__ cursor,
                                                   int* __restrict__ edgelist) {
  int t = blockIdx.x * 256 + threadIdx.x;  // 32768 pairs
  int n = idx8[t];
  int pos = atomicAdd(&cursor[n], 1);
  edgelist[pos] = t >> 3;
}

// ---------- 8. bf16 MFMA GEMM 128x128 (512 thr), optional fused edge-gather ----------
template<int OUTF32, int BNS, int GATHER>
__global__ __launch_bounds__(512) void gemm_bf16_kernel(const unsigned short* __restrict__ A,
                                                        const unsigned short* __restrict__ Wt,
                                                        const float* __restrict__ bias,
                                                        void* __restrict__ outp,
                                                        float* __restrict__ bnsum,
                                                        const int* __restrict__ idx8) {
  __shared__ ushort_t sA[128][72];
  __shared__ ushort_t sB[128][72];
  __shared__ int sIdx[128][8];
  int tid = threadIdx.x, wave = tid >> 6, lane = tid & 63;
  int wm = wave >> 2, wn = wave & 3;           // 2 x 4 waves
  int n0 = blockIdx.x * 128, m0 = blockIdx.y * 128;
  size_t bbase = 0;
  if constexpr (GATHER) {
    int e0 = m0 & 4095;
    bbase = ((size_t)(m0 >> 12) << 12) * NC;   // batch base row offset in xt
#pragma unroll
    for (int u = tid; u < 1024; u += 512) ((int*)sIdx)[u] = idx8[e0 * 8 + u];
    __syncthreads();
  }
  f4 acc[4][2];
#pragma unroll
  for (int i = 0; i < 4; ++i)
#pragma unroll
    for (int j = 0; j < 2; ++j) acc[i][j] = (f4){0.f, 0.f, 0.f, 0.f};

  for (int k0 = 0; k0 < NC; k0 += 64) {
#pragma unroll
    for (int i = 0; i < 2; ++i) {
      int u = tid + i * 512; int r = u >> 3, q = u & 7;
      int qp = (q ^ ((r >> 1) & 7)) * 8;
      if constexpr (GATHER) {
        float s[8] = {0.f,0.f,0.f,0.f,0.f,0.f,0.f,0.f};
#pragma unroll
        for (int k = 0; k < 8; ++k) {
          int nn = sIdx[r][k];
          uint4 v = *(const uint4*)&A[bbase + (size_t)nn * NC + k0 + q * 8];
          s[0] += bf2f((unsigned short)(v.x & 0xFFFF)); s[1] += bf2f((unsigned short)(v.x >> 16));
          s[2] += bf2f((unsigned short)(v.y & 0xFFFF)); s[3] += bf2f((unsigned short)(v.y >> 16));
          s[4] += bf2f((unsigned short)(v.z & 0xFFFF)); s[5] += bf2f((unsigned short)(v.z >> 16));
          s[6] += bf2f((unsigned short)(v.w & 0xFFFF)); s[7] += bf2f((unsigned short)(v.w >> 16));
        }
        uint4 o;
        o.x = (unsigned)f2bf(s[0]*0.125f) | ((unsigned)f2bf(s[1]*0.125f) << 16);
        o.y = (unsigned)f2bf(s[2]*0.125f) | ((unsigned)f2bf(s[3]*0.125f) << 16);
        o.z = (unsigned)f2bf(s[4]*0.125f) | ((unsigned)f2bf(s[5]*0.125f) << 16);
        o.w = (unsigned)f2bf(s[6]*0.125f) | ((unsigned)f2bf(s[7]*0.125f) << 16);
        *(uint4*)&sA[r][qp] = o;
      } else {
        *(uint4*)&sA[r][qp] = *(const uint4*)&A[(size_t)(m0 + r) * NC + k0 + q * 8];
      }
      *(uint4*)&sB[r][qp] = *(const uint4*)&Wt[(size_t)(n0 + r) * NC + k0 + q * 8];
    }
    __syncthreads();
#pragma unroll
    for (int ks = 0; ks < 2; ++ks) {
      int qr = ks * 4 + (lane >> 4);
      bf8 a[4], b[2];
#pragma unroll
      for (int mf = 0; mf < 4; ++mf) {
        int rr = wm*64 + mf*16 + (lane & 15);
        a[mf] = *(const bf8*)&sA[rr][(qr ^ ((rr >> 1) & 7)) * 8];
      }
#pragma unroll
      for (int nf = 0; nf < 2; ++nf) {
        int rr = wn*32 + nf*16 + (lane & 15);
        b[nf] = *(const bf8*)&sB[rr][(qr ^ ((rr >> 1) & 7)) * 8];
      }
#pragma unroll
      for (int nf = 0; nf < 2; ++nf)
#pragma unroll
        for (int mf = 0; mf < 4; ++mf)
          acc[mf][nf] = __builtin_amdgcn_mfma_f32_16x16x32_bf16(a[mf], b[nf], acc[mf][nf], 0, 0, 0);
    }
    __syncthreads();
  }
#pragma unroll
  for (int nf = 0; nf < 2; ++nf) {
    int n = n0 + wn*32 + nf*16 + (lane & 15);
    float bi = bias[n];
    float s1 = 0.f, s2 = 0.f;
#pragma unroll
    for (int mf = 0; mf < 4; ++mf) {
#pragma unroll
      for (int r = 0; r < 4; ++r) {
        int m = m0 + wm*64 + mf*16 + (lane >> 4)*4 + r;
        float v = acc[mf][nf][r] + bi;
        if (OUTF32) ((float*)outp)[(size_t)m * NC + n] = v;
        else ((unsigned short*)outp)[(size_t)m * NC + n] = f2bf(v);
        if (BNS) { s1 += v; s2 = fmaf(v, v, s2); }
      }
    }
    if (BNS) {
      s1 += __shfl_xor(s1, 16); s1 += __shfl_xor(s1, 32);
      s2 += __shfl_xor(s2, 16); s2 += __shfl_xor(s2, 32);
      if (lane < 16) {
        atomicAdd(&bnsum[n], s1);
        atomicAdd(&bnsum[NC + n], s2);
      }
    }
  }
}

// ---------- 9. node scatter (bf16): relu(1/8 sum_{e∋n} xp[b,e,:]) (+bf16 residual) ----------
template<int MODE>
__global__ __launch_bounds__(256) void scatter_kernel(const unsigned short* __restrict__ xp,
                                                      const int* __restrict__ offsets,
                                                      const int* __restrict__ edgelist,
                                                      const unsigned short* __restrict__ res,
                                                      unsigned short* __restrict__ outb) {
  int b = blockIdx.y;
  int n = blockIdx.x * 4 + (threadIdx.x >> 6);
  int lane = threadIdx.x & 63;
  int s0i = offsets[n], s1i = offsets[n + 1];
  float s0 = 0, s1 = 0, s2 = 0, s3 = 0;
  for (int j = s0i; j < s1i; ++j) {
    int e = edgelist[j];
    uint2 v = *(const uint2*)&xp[((size_t)((b << 12) + e)) * NC + lane * 4];
    s0 += bf2f((unsigned short)(v.x & 0xFFFF)); s1 += bf2f((unsigned short)(v.x >> 16));
    s2 += bf2f((unsigned short)(v.y & 0xFFFF)); s3 += bf2f((unsigned short)(v.y >> 16));
  }
  s0 = fmaxf(s0 * 0.125f, 0.f); s1 = fmaxf(s1 * 0.125f, 0.f);
  s2 = fmaxf(s2 * 0.125f, 0.f); s3 = fmaxf(s3 * 0.125f, 0.f);
  size_t o = ((size_t)((b << 12) + n)) * NC + lane * 4;
  if (MODE == 1) {
    uint2 v = *(const uint2*)&res[o];
    s0 += bf2f((unsigned short)(v.x & 0xFFFF)); s1 += bf2f((unsigned short)(v.x >> 16));
    s2 += bf2f((unsigned short)(v.y & 0xFFFF)); s3 += bf2f((unsigned short)(v.y >> 16));
  }
  uint2 ov;
  ov.x = (unsigned)f2bf(s0) | ((unsigned)f2bf(s1) << 16);
  ov.y = (unsigned)f2bf(s2) | ((unsigned)f2bf(s3) << 16);
  *(uint2*)&outb[o] = ov;
}

// ---------- 10. transpose + BN (inline stats->affine) + residual ----------
__global__ __launch_bounds__(256) void final_kernel(const float* __restrict__ y,
                                                    const float* __restrict__ feat,
                                                    const float* __restrict__ bnsum,
                                                    const float* __restrict__ gam,
                                                    const float* __restrict__ bet,
                                                    float* __restrict__ out) {
  __shared__ float tile[64][65];
  __shared__ float sa_[64], sb_[64];
  int n0 = blockIdx.x * 64;
  int c0 = blockIdx.y * 64;
  int b  = blockIdx.z;
  int tid = threadIdx.x;
  if (tid < 64) {
    const float invn = 1.f / (float)(NB * NN);
    int c = c0 + tid;
    float mean = bnsum[c] * invn;
    float var  = bnsum[NC + c] * invn - mean * mean;
    float a = gam[c] * rsqrtf(var + 1e-5f);
    sa_[tid] = a;
    sb_[tid] = bet[c] - mean * a;
  }
  int n_l = tid >> 2;
  int q   = tid & 3;
  const float4* y4 = (const float4*)y;
#pragma unroll
  for (int i = 0; i < 4; ++i) {
    int cl = q * 16 + i * 4;
    float4 v = y4[(size_t)(b * NN + n0 + n_l) * 64 + ((c0 + cl) >> 2)];
    tile[n_l][cl+0] = v.x; tile[n_l][cl+1] = v.y; tile[n_l][cl+2] = v.z; tile[n_l][cl+3] = v.w;
  }
  __syncthreads();
  int cl2 = tid >> 6;
  int nl2 = tid & 63;
#pragma unroll
  for (int p = 0; p < 16; ++p) {
    int ci = p * 4 + cl2;
    float a = sa_[ci], bb = sb_[ci];
    size_t o = (size_t)b * (NC * NN) + (size_t)(c0 + ci) * NN + n0 + nl2;
    out[o] = feat[o] + fmaf(a, tile[nl2][ci], bb);
  }
}

}  // namespace

extern "C" void kernel_launch(void* const* d_in, const int* in_sizes, int n_in,
                              void* d_out, int out_size, void* d_ws, size_t ws_size,
                              hipStream_t stream) {
  (void)in_sizes; (void)n_in; (void)out_size; (void)ws_size;
  const float* feat = (const float*)d_in[0];
  const float* t0w  = (const float*)d_in[1];
  const float* t0b  = (const float*)d_in[2];
  const float* p0w  = (const float*)d_in[3];
  const float* p0b  = (const float*)d_in[4];
  const float* t1w  = (const float*)d_in[5];
  const float* t1b  = (const float*)d_in[6];
  const float* p1w  = (const float*)d_in[7];
  const float* p1b  = (const float*)d_in[8];
  const float* pw   = (const float*)d_in[9];
  const float* pb   = (const float*)d_in[10];
  const float* gam  = (const float*)d_in[11];
  const float* bet  = (const float*)d_in[12];
  float* out = (float*)d_out;

  // workspace layout (~77 MiB)
  char* ws = (char*)d_ws;
  float*          y   = (float*)ws;                          // 16 MiB fp32 [B*N][C]
  unsigned short* xin = (unsigned short*)(ws + (16u << 20)); // 8 MiB each
  unsigned short* xt  = (unsigned short*)(ws + (24u << 20));
  unsigned short* xp  = (unsigned short*)(ws + (40u << 20));
  unsigned short* x1  = (unsigned short*)(ws + (48u << 20));
  unsigned short* x2  = (unsigned short*)(ws + (56u << 20));
  unsigned short* Xhi = (unsigned short*)(ws + (64u << 20)); // 2 MiB
  unsigned short* Xlo = (unsigned short*)(ws + (66u << 20)); // 2 MiB
  ull*            cand = (ull*)(ws + (68u << 20));           // 8 MiB (4096*256 ull)
  char* sm = ws + (76u << 20);
  unsigned short* Wt  = (unsigned short*)sm;                 // 5*128 KiB
  int*   idx8     = (int*)(sm + 655360);                     // 128 KiB
  int*   counts   = (int*)(sm + 786432);                     // 16 KiB
  int*   offsets  = (int*)(sm + 802816);                     // 16 KiB + 4
  int*   cursor   = (int*)(sm + 819456);                     // 16 KiB
  int*   edgelist = (int*)(sm + 835840);                     // 128 KiB
  float* inv      = (float*)(sm + 966912);                   // 16 KiB
  float* bnsum    = (float*)(sm + 983296);                   // 2 KiB

  norm_kernel<<<NN / 256, 256, 0, stream>>>(feat, inv, counts, bnsum);
  feat2bf_kernel<<<dim3(64, 4, 4), 256, 0, stream>>>(feat, inv, xin, Xhi, Xlo);
  wcvt_kernel<<<dim3(4, 4, 5), 256, 0, stream>>>(t0w, p0w, t1w, p1w, pw, Wt);

  // symmetric fused sim + per-tile top-8 (upper triangle only)
  simtop_kernel<<<528, 512, 0, stream>>>(Xhi, Xlo, cand);
  merge_kernel<<<128, 256, 0, stream>>>(cand, idx8, counts);
  scan_kernel<<<1, 256, 0, stream>>>(counts, offsets, cursor);
  fill_kernel<<<128, 256, 0, stream>>>(idx8, cursor, edgelist);

  // layer 0: theta -> (fused gather+phi) -> scatter
  gemm_bf16_kernel<0,0,0><<<dim3(2, 128), 512, 0, stream>>>(xin, Wt + 0*65536, t0b, xt, nullptr, nullptr);
  gemm_bf16_kernel<0,0,1><<<dim3(2, 128), 512, 0, stream>>>(xt,  Wt + 1*65536, p0b, xp, nullptr, idx8);
  scatter_kernel<0><<<dim3(1024, 4), 256, 0, stream>>>(xp, offsets, edgelist, nullptr, x1);
  // layer 1
  gemm_bf16_kernel<0,0,0><<<dim3(2, 128), 512, 0, stream>>>(x1, Wt + 2*65536, t1b, xt, nullptr, nullptr);
  gemm_bf16_kernel<0,0,1><<<dim3(2, 128), 512, 0, stream>>>(xt, Wt + 3*65536, p1b, xp, nullptr, idx8);
  scatter_kernel<1><<<dim3(1024, 4), 256, 0, stream>>>(xp, offsets, edgelist, x1, x2);
  // proj (fp32 out) + fused BN stats
  gemm_bf16_kernel<1,1,0><<<dim3(2, 128), 512, 0, stream>>>(x2, Wt + 4*65536, pb, y, bnsum, nullptr);

  final_kernel<<<dim3(64, 4, 4), 256, 0, stream>>>(y, feat, bnsum, gam, bet, out);
}

// Round 8
// 307.712 us; speedup vs baseline: 1.1129x; 1.1129x over previous
//
#include <hip/hip_runtime.h>

namespace {

constexpr int NB = 4;
constexpr int NC = 256;   // C == HID
constexpr int NN = 4096;  // 64*64

typedef __attribute__((ext_vector_type(8))) short bf8;
typedef __attribute__((ext_vector_type(4))) float f4;
typedef unsigned short ushort_t;
typedef unsigned long long ull;

__device__ __forceinline__ float bf2f(unsigned short u) {
  return __uint_as_float(((unsigned)u) << 16);
}
__device__ __forceinline__ unsigned short f2bf(float f) {  // RNE
  unsigned x = __float_as_uint(f);
  return (unsigned short)((x + 0x7FFFu + ((x >> 16) & 1u)) >> 16);
}
__device__ __forceinline__ unsigned enc_f(float f) {
  unsigned u = __float_as_uint(f);
  return (u & 0x80000000u) ? ~u : (u | 0x80000000u);  // monotonic float->uint
}

// branch-free sorted-descending top-8 insert on fp64 keys.
// Keys are 44-bit integers ((enc<<12)|(0xFFF-idx)) held exactly in doubles;
// fmax/fmin return operands bit-exactly -> exact lexicographic selection.
__device__ __forceinline__ void insd(double* b, double k) {
  b[7] = fmax(b[7], k);
#pragma unroll
  for (int p = 7; p >= 1; --p) {
    double hi = fmax(b[p-1], b[p]);
    double lo = fmin(b[p-1], b[p]);
    b[p-1] = hi; b[p] = lo;
  }
}

__device__ __forceinline__ double shfl_xor_d(double v, int m) {
  ull u = __double_as_longlong(v);
  unsigned lo = (unsigned)(u & 0xFFFFFFFFull), hi = (unsigned)(u >> 32);
  lo = (unsigned)__shfl_xor((int)lo, m);
  hi = (unsigned)__shfl_xor((int)hi, m);
  return __longlong_as_double(((ull)hi << 32) | (ull)lo);
}

template<int MAXS>
__device__ __forceinline__ void shfl_merged(double* b) {
#pragma unroll
  for (int s = 1; s <= MAXS; s <<= 1) {
    double tmp[8];
#pragma unroll
    for (int k = 0; k < 8; ++k) tmp[k] = shfl_xor_d(b[k], s);
#pragma unroll
    for (int k = 0; k < 8; ++k) insd(b, tmp[k]);
  }
}

// ---------- 1. inverse row norms of batch-0 features (+ zero counts/bnsum) ----------
__global__ __launch_bounds__(256) void norm_kernel(const float* __restrict__ feat,
                                                   float* __restrict__ inv,
                                                   int* __restrict__ counts,
                                                   float* __restrict__ bnsum) {
  int n = blockIdx.x * 256 + threadIdx.x;
  counts[n] = 0;
  if (n < 2 * NC) bnsum[n] = 0.f;
  float ss = 0.f;
  for (int c = 0; c < NC; ++c) { float v = feat[(size_t)c * NN + n]; ss = fmaf(v, v, ss); }
  inv[n] = 1.f / fmaxf(sqrtf(ss), 1e-12f);
}

// ---------- 2. feat [B][C][N] -> xin [B*N][C] bf16 ; b==0 also emits Xhi/Xlo ----------
__global__ __launch_bounds__(256) void feat2bf_kernel(const float* __restrict__ feat,
                                                      const float* __restrict__ inv,
                                                      unsigned short* __restrict__ xin,
                                                      unsigned short* __restrict__ Xhi,
                                                      unsigned short* __restrict__ Xlo) {
  __shared__ float tile[64][65];
  int n0 = blockIdx.x * 64, c0 = blockIdx.y * 64, b = blockIdx.z;
  int tid = threadIdx.x;
#pragma unroll
  for (int i = 0; i < 4; ++i) {
    int u = tid + i * 256; int cr = u >> 4, q = u & 15;
    float4 v = *(const float4*)&feat[((size_t)b * NC + c0 + cr) * NN + n0 + q * 4];
    tile[cr][q*4+0] = v.x; tile[cr][q*4+1] = v.y; tile[cr][q*4+2] = v.z; tile[cr][q*4+3] = v.w;
  }
  __syncthreads();
#pragma unroll
  for (int i = 0; i < 4; ++i) {
    int u = tid + i * 256; int nr = u >> 4, q = u & 15;
    float x0 = tile[q*4+0][nr], x1 = tile[q*4+1][nr];
    float x2 = tile[q*4+2][nr], x3 = tile[q*4+3][nr];
    ushort4 o;
    o.x = f2bf(x0); o.y = f2bf(x1); o.z = f2bf(x2); o.w = f2bf(x3);
    *(ushort4*)&xin[((size_t)(b << 12) + n0 + nr) * NC + c0 + q * 4] = o;
    if (b == 0) {
      float iv = inv[n0 + nr];
      float y0 = x0 * iv, y1 = x1 * iv, y2 = x2 * iv, y3 = x3 * iv;
      ushort4 h, l;
      h.x = f2bf(y0); l.x = f2bf(y0 - bf2f(h.x));
      h.y = f2bf(y1); l.y = f2bf(y1 - bf2f(h.y));
      h.z = f2bf(y2); l.z = f2bf(y2 - bf2f(h.z));
      h.w = f2bf(y3); l.w = f2bf(y3 - bf2f(h.w));
      size_t oo = (size_t)(n0 + nr) * NC + c0 + q * 4;
      *(ushort4*)&Xhi[oo] = h;
      *(ushort4*)&Xlo[oo] = l;
    }
  }
}

// ---------- 3. weight convert: W[k][n] fp32 -> Wt[n][k] bf16 (5 matrices) ----------
__global__ __launch_bounds__(256) void wcvt_kernel(const float* __restrict__ w0,
                                                   const float* __restrict__ w1,
                                                   const float* __restrict__ w2,
                                                   const float* __restrict__ w3,
                                                   const float* __restrict__ w4,
                                                   unsigned short* __restrict__ Wt) {
  __shared__ float tile[64][65];
  int z = blockIdx.z;
  const float* W = (z == 0) ? w0 : (z == 1) ? w1 : (z == 2) ? w2 : (z == 3) ? w3 : w4;
  int k0 = blockIdx.x * 64, n0 = blockIdx.y * 64;
  int tid = threadIdx.x;
#pragma unroll
  for (int i = 0; i < 4; ++i) {
    int u = tid + i * 256; int kr = u >> 4, q = u & 15;
    float4 v = *(const float4*)&W[(size_t)(k0 + kr) * NC + n0 + q * 4];
    tile[kr][q*4+0] = v.x; tile[kr][q*4+1] = v.y; tile[kr][q*4+2] = v.z; tile[kr][q*4+3] = v.w;
  }
  __syncthreads();
#pragma unroll
  for (int i = 0; i < 4; ++i) {
    int u = tid + i * 256; int nr = u >> 4, q = u & 15;
    ushort4 o;
    o.x = f2bf(tile[q*4+0][nr]); o.y = f2bf(tile[q*4+1][nr]);
    o.z = f2bf(tile[q*4+2][nr]); o.w = f2bf(tile[q*4+3][nr]);
    *(ushort4*)&Wt[(size_t)z * 65536 + (size_t)(n0 + nr) * NC + k0 + q * 4] = o;
  }
}

// ---------- 4. symmetric fused sim (split-bf16 MFMA) + dual top-8 extraction ----------
// 528 upper-triangle 128x128 blocks. K-step 32 -> 40960 B LDS (3-4 blocks/CU).
// Extraction in two 64-row halves over simT[64][132]; fp64-key branch-free top-8.
__global__ __launch_bounds__(512, 6) void simtop_kernel(const unsigned short* __restrict__ Xhi,
                                                        const unsigned short* __restrict__ Xlo,
                                                        double* __restrict__ cand) {
  __shared__ __align__(16) char lds[40960];
  // staging: 4 buffers of [128][40] shorts at 0 / 10240 / 20480 / 30720
  float (*simT)[132] = (float(*)[132])(lds);   // [64][132] f32 = 33792 B, aliases staging

  int tid = threadIdx.x, wave = tid >> 6, lane = tid & 63;
  int wm = wave >> 2, wn = wave & 3;   // 2 x 4 waves, wave tile 64x32
  int orig = blockIdx.x;
  int bid = (orig & 7) * 66 + (orig >> 3);  // XCD-chunked bijection (528 = 8*66)
  int pi = (int)((sqrtf(8.f * (float)bid + 1.f) - 1.f) * 0.5f);
  while ((pi + 1) * (pi + 2) / 2 <= bid) ++pi;
  while (pi * (pi + 1) / 2 > bid) --pi;
  int pj = bid - pi * (pi + 1) / 2;
  int m0 = pj * 128, n0 = pi * 128;

  // staging map: row sr = tid>>2, 16B chunk q = tid&3 (k-step = 32 halves = 4 chunks)
  int sr = tid >> 2;
  int q  = tid & 3;
  int qp = q ^ (sr & 3);                        // XOR-swizzled slot
  const ushort_t* gAh = Xhi + (size_t)(m0 + sr) * NC + q * 8;
  const ushort_t* gAl = Xlo + (size_t)(m0 + sr) * NC + q * 8;
  const ushort_t* gBh = Xhi + (size_t)(n0 + sr) * NC + q * 8;
  const ushort_t* gBl = Xlo + (size_t)(n0 + sr) * NC + q * 8;
  int dst = sr * 80 + qp * 16;                  // byte offset within buffer

  f4 acc[4][2];
#pragma unroll
  for (int i = 0; i < 4; ++i)
#pragma unroll
    for (int j = 0; j < 2; ++j) acc[i][j] = (f4){0.f, 0.f, 0.f, 0.f};

#pragma unroll
  for (int kk = 0; kk < 8; ++kk) {              // 8 k-steps of 32
    uint4 a0 = *(const uint4*)(gAh + kk * 32);
    uint4 a1 = *(const uint4*)(gAl + kk * 32);
    uint4 b0 = *(const uint4*)(gBh + kk * 32);
    uint4 b1 = *(const uint4*)(gBl + kk * 32);
    *(uint4*)(lds +     0 + dst) = a0;
    *(uint4*)(lds + 10240 + dst) = a1;
    *(uint4*)(lds + 20480 + dst) = b0;
    *(uint4*)(lds + 30720 + dst) = b1;
    __syncthreads();
    {
      int qr = lane >> 4;                       // k-chunk 0..3
      bf8 ah[4], al[4], bh[2], bl[2];
#pragma unroll
      for (int mf = 0; mf < 4; ++mf) {
        int rr = wm*64 + mf*16 + (lane & 15);
        int off = rr * 80 + ((qr ^ (rr & 3)) * 16);
        ah[mf] = *(const bf8*)(lds +     0 + off);
        al[mf] = *(const bf8*)(lds + 10240 + off);
      }
#pragma unroll
      for (int nf = 0; nf < 2; ++nf) {
        int rr = wn*32 + nf*16 + (lane & 15);
        int off = rr * 80 + ((qr ^ (rr & 3)) * 16);
        bh[nf] = *(const bf8*)(lds + 20480 + off);
        bl[nf] = *(const bf8*)(lds + 30720 + off);
      }
#pragma unroll
      for (int nf = 0; nf < 2; ++nf)
#pragma unroll
        for (int mf = 0; mf < 4; ++mf) {
          acc[mf][nf] = __builtin_amdgcn_mfma_f32_16x16x32_bf16(ah[mf], bh[nf], acc[mf][nf], 0, 0, 0);
          acc[mf][nf] = __builtin_amdgcn_mfma_f32_16x16x32_bf16(ah[mf], bl[nf], acc[mf][nf], 0, 0, 0);
          acc[mf][nf] = __builtin_amdgcn_mfma_f32_16x16x32_bf16(al[mf], bh[nf], acc[mf][nf], 0, 0, 0);
        }
    }
    __syncthreads();
  }

  // ======== extraction in two 64-row halves ========
  double c8[8];
  int ccol = 0, cseg = 0;
  bool docol = (pi != pj) && (tid >= 256);
  if (docol) {
    ccol = (tid - 256) >> 1; cseg = tid & 1;
#pragma unroll
    for (int k = 0; k < 8; ++k) c8[k] = 0.0;
  }

#pragma unroll
  for (int h = 0; h < 2; ++h) {
    if (h) __syncthreads();                     // protect simT from prior readers
    if (wm == h) {                              // spill this half's rows (local 0..63)
#pragma unroll
      for (int mf = 0; mf < 4; ++mf)
#pragma unroll
        for (int nf = 0; nf < 2; ++nf) {
          int cl = wn*32 + nf*16 + (lane & 15);
          int rb = mf*16 + (lane >> 4)*4;
#pragma unroll
          for (int r = 0; r < 4; ++r) simT[rb + r][cl] = acc[mf][nf][r];
        }
    }
    __syncthreads();
    if (tid < 256) {
      // row extract: 64 rows x 4 thr, 32 values each (staggered float4)
      int rl = tid >> 2, q4 = tid & 3;
      const float* rowp = &simT[rl][q4 * 32];
      double b8[8] = {0,0,0,0,0,0,0,0};
#pragma unroll
      for (int i = 0; i < 8; ++i) {
        int off = ((i + q4 * 2) & 7) * 4;
        float4 v = *(const float4*)(rowp + off);
        unsigned jb = 0xFFFu - (unsigned)(n0 + q4 * 32 + off);
        insd(b8, (double)((((ull)enc_f(v.x)) << 12) | (ull)(jb    )));
        insd(b8, (double)((((ull)enc_f(v.y)) << 12) | (ull)(jb - 1)));
        insd(b8, (double)((((ull)enc_f(v.z)) << 12) | (ull)(jb - 2)));
        insd(b8, (double)((((ull)enc_f(v.w)) << 12) | (ull)(jb - 3)));
      }
      shfl_merged<2>(b8);
      if (q4 == 0) {
        double* dp = cand + (size_t)(m0 + h * 64 + rl) * 256 + pi * 8;
#pragma unroll
        for (int k = 0; k < 8; ++k) dp[k] = b8[k];
      }
    } else if (docol) {
      // col extract: 128 cols x 2 thr over this half's 64 rows (c8 persists)
#pragma unroll
      for (int i = 0; i < 32; ++i) {
        int ir = (i + cseg * 7) & 31;           // stagger
        int rloc = cseg * 32 + ir;
        float v = simT[rloc][ccol];
        unsigned jb = 0xFFFu - (unsigned)(m0 + h * 64 + rloc);
        insd(c8, (double)((((ull)enc_f(v)) << 12) | (ull)jb));
      }
    }
  }
  if (docol) {
    shfl_merged<1>(c8);
    if (cseg == 0) {
      double* dp = cand + (size_t)(n0 + ccol) * 256 + pj * 8;
#pragma unroll
      for (int k = 0; k < 8; ++k) dp[k] = c8[k];
    }
  }
}

// ---------- 5. merge per-tile candidates -> exact global top-8 (+ counts) ----------
__global__ __launch_bounds__(256) void merge_kernel(const double* __restrict__ cand,
                                                    int* __restrict__ idx8,
                                                    int* __restrict__ counts) {
  int t = blockIdx.x * 256 + threadIdx.x;   // 32768 = 4096 rows x 8
  int row = t >> 3, part = t & 7;
  const double* cp = cand + (size_t)row * 256 + part * 32;
  double b8[8] = {0,0,0,0,0,0,0,0};
  for (int g = 0; g < 4; ++g) {
#pragma unroll 1
    for (int k = 0; k < 8; ++k) {
      double key = cp[g * 8 + k];
      if (key <= b8[7]) break;                  // chunk sorted desc -> exact early exit
      insd(b8, key);
    }
  }
  shfl_merged<4>(b8);
  if (part == 0) {
#pragma unroll
    for (int k = 0; k < 8; ++k) {
      ull K = (ull)b8[k];                       // exact: 44-bit integer
      int j = 0xFFF - (int)(K & 0xFFFull);
      idx8[row * 8 + k] = j;
      atomicAdd(&counts[j], 1);
    }
  }
}

// ---------- 6. CSR prefix scan (exclusive) + cursor init ----------
__global__ __launch_bounds__(256) void scan_kernel(const int* __restrict__ counts,
                                                   int* __restrict__ offsets,
                                                   int* __restrict__ cursor) {
  __shared__ int ssum[256];
  __shared__ int sbase[257];
  int t = threadIdx.x;
  int loc[16];
  int s = 0;
#pragma unroll
  for (int i = 0; i < 16; ++i) { loc[i] = s; s += counts[t*16 + i]; }
  ssum[t] = s;
  __syncthreads();
  if (t == 0) {
    int acc = 0;
    for (int i = 0; i < 256; ++i) { sbase[i] = acc; acc += ssum[i]; }
    sbase[256] = acc;
  }
  __syncthreads();
  int b0 = sbase[t];
#pragma unroll
  for (int i = 0; i < 16; ++i) {
    int off = b0 + loc[i];
    offsets[t*16 + i] = off;
    cursor [t*16 + i] = off;
  }
  if (t == 0) offsets[NN] = sbase[256];
}

// ---------- 7. CSR fill ----------
__global__ __launch_bounds__(256) void fill_kernel(const int* __restrict__ idx8,
                                                   int* __restrict__ cursor,
                                                   int* __restrict__ edgelist) {
  int t = blockIdx.x * 256 + threadIdx.x;  // 32768 pairs
  int n = idx8[t];
  int pos = atomicAdd(&cursor[n], 1);
  edgelist[pos] = t >> 3;
}

// ---------- 8. bf16 MFMA GEMM 128x128 (512 thr), optional fused edge-gather ----------
template<int OUTF32, int BNS, int GATHER>
__global__ __launch_bounds__(512) void gemm_bf16_kernel(const unsigned short* __restrict__ A,
                                                        const unsigned short* __restrict__ Wt,
                                                        const float* __restrict__ bias,
                                                        void* __restrict__ outp,
                                                        float* __restrict__ bnsum,
                                                        const int* __restrict__ idx8) {
  __shared__ ushort_t sA[128][72];
  __shared__ ushort_t sB[128][72];
  __shared__ int sIdx[128][8];
  int tid = threadIdx.x, wave = tid >> 6, lane = tid & 63;
  int wm = wave >> 2, wn = wave & 3;           // 2 x 4 waves
  int n0 = blockIdx.x * 128, m0 = blockIdx.y * 128;
  size_t bbase = 0;
  if constexpr (GATHER) {
    int e0 = m0 & 4095;
    bbase = ((size_t)(m0 >> 12) << 12) * NC;   // batch base row offset in xt
#pragma unroll
    for (int u = tid; u < 1024; u += 512) ((int*)sIdx)[u] = idx8[e0 * 8 + u];
    __syncthreads();
  }
  f4 acc[4][2];
#pragma unroll
  for (int i = 0; i < 4; ++i)
#pragma unroll
    for (int j = 0; j < 2; ++j) acc[i][j] = (f4){0.f, 0.f, 0.f, 0.f};

  for (int k0 = 0; k0 < NC; k0 += 64) {
#pragma unroll
    for (int i = 0; i < 2; ++i) {
      int u = tid + i * 512; int r = u >> 3; int qq = u & 7;
      int qp = (qq ^ ((r >> 1) & 7)) * 8;
      if constexpr (GATHER) {
        float s[8] = {0.f,0.f,0.f,0.f,0.f,0.f,0.f,0.f};
#pragma unroll
        for (int k = 0; k < 8; ++k) {
          int nn = sIdx[r][k];
          uint4 v = *(const uint4*)&A[bbase + (size_t)nn * NC + k0 + qq * 8];
          s[0] += bf2f((unsigned short)(v.x & 0xFFFF)); s[1] += bf2f((unsigned short)(v.x >> 16));
          s[2] += bf2f((unsigned short)(v.y & 0xFFFF)); s[3] += bf2f((unsigned short)(v.y >> 16));
          s[4] += bf2f((unsigned short)(v.z & 0xFFFF)); s[5] += bf2f((unsigned short)(v.z >> 16));
          s[6] += bf2f((unsigned short)(v.w & 0xFFFF)); s[7] += bf2f((unsigned short)(v.w >> 16));
        }
        uint4 o;
        o.x = (unsigned)f2bf(s[0]*0.125f) | ((unsigned)f2bf(s[1]*0.125f) << 16);
        o.y = (unsigned)f2bf(s[2]*0.125f) | ((unsigned)f2bf(s[3]*0.125f) << 16);
        o.z = (unsigned)f2bf(s[4]*0.125f) | ((unsigned)f2bf(s[5]*0.125f) << 16);
        o.w = (unsigned)f2bf(s[6]*0.125f) | ((unsigned)f2bf(s[7]*0.125f) << 16);
        *(uint4*)&sA[r][qp] = o;
      } else {
        *(uint4*)&sA[r][qp] = *(const uint4*)&A[(size_t)(m0 + r) * NC + k0 + qq * 8];
      }
      *(uint4*)&sB[r][qp] = *(const uint4*)&Wt[(size_t)(n0 + r) * NC + k0 + qq * 8];
    }
    __syncthreads();
#pragma unroll
    for (int ks = 0; ks < 2; ++ks) {
      int qr = ks * 4 + (lane >> 4);
      bf8 a[4], b[2];
#pragma unroll
      for (int mf = 0; mf < 4; ++mf) {
        int rr = wm*64 + mf*16 + (lane & 15);
        a[mf] = *(const bf8*)&sA[rr][(qr ^ ((rr >> 1) & 7)) * 8];
      }
#pragma unroll
      for (int nf = 0; nf < 2; ++nf) {
        int rr = wn*32 + nf*16 + (lane & 15);
        b[nf] = *(const bf8*)&sB[rr][(qr ^ ((rr >> 1) & 7)) * 8];
      }
#pragma unroll
      for (int nf = 0; nf < 2; ++nf)
#pragma unroll
        for (int mf = 0; mf < 4; ++mf)
          acc[mf][nf] = __builtin_amdgcn_mfma_f32_16x16x32_bf16(a[mf], b[nf], acc[mf][nf], 0, 0, 0);
    }
    __syncthreads();
  }
#pragma unroll
  for (int nf = 0; nf < 2; ++nf) {
    int n = n0 + wn*32 + nf*16 + (lane & 15);
    float bi = bias[n];
    float s1 = 0.f, s2 = 0.f;
#pragma unroll
    for (int mf = 0; mf < 4; ++mf) {
#pragma unroll
      for (int r = 0; r < 4; ++r) {
        int m = m0 + wm*64 + mf*16 + (lane >> 4)*4 + r;
        float v = acc[mf][nf][r] + bi;
        if (OUTF32) ((float*)outp)[(size_t)m * NC + n] = v;
        else ((unsigned short*)outp)[(size_t)m * NC + n] = f2bf(v);
        if (BNS) { s1 += v; s2 = fmaf(v, v, s2); }
      }
    }
    if (BNS) {
      s1 += __shfl_xor(s1, 16); s1 += __shfl_xor(s1, 32);
      s2 += __shfl_xor(s2, 16); s2 += __shfl_xor(s2, 32);
      if (lane < 16) {
        atomicAdd(&bnsum[n], s1);
        atomicAdd(&bnsum[NC + n], s2);
      }
    }
  }
}

// ---------- 9. node scatter (bf16): relu(1/8 sum_{e∋n} xp[b,e,:]) (+bf16 residual) ----------
template<int MODE>
__global__ __launch_bounds__(256) void scatter_kernel(const unsigned short* __restrict__ xp,
                                                      const int* __restrict__ offsets,
                                                      const int* __restrict__ edgelist,
                                                      const unsigned short* __restrict__ res,
                                                      unsigned short* __restrict__ outb) {
  int b = blockIdx.y;
  int n = blockIdx.x * 4 + (threadIdx.x >> 6);
  int lane = threadIdx.x & 63;
  int s0i = offsets[n], s1i = offsets[n + 1];
  float s0 = 0, s1 = 0, s2 = 0, s3 = 0;
  for (int j = s0i; j < s1i; ++j) {
    int e = edgelist[j];
    uint2 v = *(const uint2*)&xp[((size_t)((b << 12) + e)) * NC + lane * 4];
    s0 += bf2f((unsigned short)(v.x & 0xFFFF)); s1 += bf2f((unsigned short)(v.x >> 16));
    s2 += bf2f((unsigned short)(v.y & 0xFFFF)); s3 += bf2f((unsigned short)(v.y >> 16));
  }
  s0 = fmaxf(s0 * 0.125f, 0.f); s1 = fmaxf(s1 * 0.125f, 0.f);
  s2 = fmaxf(s2 * 0.125f, 0.f); s3 = fmaxf(s3 * 0.125f, 0.f);
  size_t o = ((size_t)((b << 12) + n)) * NC + lane * 4;
  if (MODE == 1) {
    uint2 v = *(const uint2*)&res[o];
    s0 += bf2f((unsigned short)(v.x & 0xFFFF)); s1 += bf2f((unsigned short)(v.x >> 16));
    s2 += bf2f((unsigned short)(v.y & 0xFFFF)); s3 += bf2f((unsigned short)(v.y >> 16));
  }
  uint2 ov;
  ov.x = (unsigned)f2bf(s0) | ((unsigned)f2bf(s1) << 16);
  ov.y = (unsigned)f2bf(s2) | ((unsigned)f2bf(s3) << 16);
  *(uint2*)&outb[o] = ov;
}

// ---------- 10. transpose + BN (inline stats->affine) + residual ----------
__global__ __launch_bounds__(256) void final_kernel(const float* __restrict__ y,
                                                    const float* __restrict__ feat,
                                                    const float* __restrict__ bnsum,
                                                    const float* __restrict__ gam,
                                                    const float* __restrict__ bet,
                                                    float* __restrict__ out) {
  __shared__ float tile[64][65];
  __shared__ float sa_[64], sb_[64];
  int n0 = blockIdx.x * 64;
  int c0 = blockIdx.y * 64;
  int b  = blockIdx.z;
  int tid = threadIdx.x;
  if (tid < 64) {
    const float invn = 1.f / (float)(NB * NN);
    int c = c0 + tid;
    float mean = bnsum[c] * invn;
    float var  = bnsum[NC + c] * invn - mean * mean;
    float a = gam[c] * rsqrtf(var + 1e-5f);
    sa_[tid] = a;
    sb_[tid] = bet[c] - mean * a;
  }
  int n_l = tid >> 2;
  int q   = tid & 3;
  const float4* y4 = (const float4*)y;
#pragma unroll
  for (int i = 0; i < 4; ++i) {
    int cl = q * 16 + i * 4;
    float4 v = y4[(size_t)(b * NN + n0 + n_l) * 64 + ((c0 + cl) >> 2)];
    tile[n_l][cl+0] = v.x; tile[n_l][cl+1] = v.y; tile[n_l][cl+2] = v.z; tile[n_l][cl+3] = v.w;
  }
  __syncthreads();
  int cl2 = tid >> 6;
  int nl2 = tid & 63;
#pragma unroll
  for (int p = 0; p < 16; ++p) {
    int ci = p * 4 + cl2;
    float a = sa_[ci], bb = sb_[ci];
    size_t o = (size_t)b * (NC * NN) + (size_t)(c0 + ci) * NN + n0 + nl2;
    out[o] = feat[o] + fmaf(a, tile[nl2][ci], bb);
  }
}

}  // namespace

extern "C" void kernel_launch(void* const* d_in, const int* in_sizes, int n_in,
                              void* d_out, int out_size, void* d_ws, size_t ws_size,
                              hipStream_t stream) {
  (void)in_sizes; (void)n_in; (void)out_size; (void)ws_size;
  const float* feat = (const float*)d_in[0];
  const float* t0w  = (const float*)d_in[1];
  const float* t0b  = (const float*)d_in[2];
  const float* p0w  = (const float*)d_in[3];
  const float* p0b  = (const float*)d_in[4];
  const float* t1w  = (const float*)d_in[5];
  const float* t1b  = (const float*)d_in[6];
  const float* p1w  = (const float*)d_in[7];
  const float* p1b  = (const float*)d_in[8];
  const float* pw   = (const float*)d_in[9];
  const float* pb   = (const float*)d_in[10];
  const float* gam  = (const float*)d_in[11];
  const float* bet  = (const float*)d_in[12];
  float* out = (float*)d_out;

  // workspace layout (~77 MiB)
  char* ws = (char*)d_ws;
  float*          y   = (float*)ws;                          // 16 MiB fp32 [B*N][C]
  unsigned short* xin = (unsigned short*)(ws + (16u << 20)); // 8 MiB each
  unsigned short* xt  = (unsigned short*)(ws + (24u << 20));
  unsigned short* xp  = (unsigned short*)(ws + (40u << 20));
  unsigned short* x1  = (unsigned short*)(ws + (48u << 20));
  unsigned short* x2  = (unsigned short*)(ws + (56u << 20));
  unsigned short* Xhi = (unsigned short*)(ws + (64u << 20)); // 2 MiB
  unsigned short* Xlo = (unsigned short*)(ws + (66u << 20)); // 2 MiB
  double*         cand = (double*)(ws + (68u << 20));        // 8 MiB (4096*256 f64)
  char* sm = ws + (76u << 20);
  unsigned short* Wt  = (unsigned short*)sm;                 // 5*128 KiB
  int*   idx8     = (int*)(sm + 655360);                     // 128 KiB
  int*   counts   = (int*)(sm + 786432);                     // 16 KiB
  int*   offsets  = (int*)(sm + 802816);                     // 16 KiB + 4
  int*   cursor   = (int*)(sm + 819456);                     // 16 KiB
  int*   edgelist = (int*)(sm + 835840);                     // 128 KiB
  float* inv      = (float*)(sm + 966912);                   // 16 KiB
  float* bnsum    = (float*)(sm + 983296);                   // 2 KiB

  norm_kernel<<<NN / 256, 256, 0, stream>>>(feat, inv, counts, bnsum);
  feat2bf_kernel<<<dim3(64, 4, 4), 256, 0, stream>>>(feat, inv, xin, Xhi, Xlo);
  wcvt_kernel<<<dim3(4, 4, 5), 256, 0, stream>>>(t0w, p0w, t1w, p1w, pw, Wt);

  // symmetric fused sim + per-tile top-8 (upper triangle only)
  simtop_kernel<<<528, 512, 0, stream>>>(Xhi, Xlo, cand);
  merge_kernel<<<128, 256, 0, stream>>>(cand, idx8, counts);
  scan_kernel<<<1, 256, 0, stream>>>(counts, offsets, cursor);
  fill_kernel<<<128, 256, 0, stream>>>(idx8, cursor, edgelist);

  // layer 0: theta -> (fused gather+phi) -> scatter
  gemm_bf16_kernel<0,0,0><<<dim3(2, 128), 512, 0, stream>>>(xin, Wt + 0*65536, t0b, xt, nullptr, nullptr);
  gemm_bf16_kernel<0,0,1><<<dim3(2, 128), 512, 0, stream>>>(xt,  Wt + 1*65536, p0b, xp, nullptr, idx8);
  scatter_kernel<0><<<dim3(1024, 4), 256, 0, stream>>>(xp, offsets, edgelist, nullptr, x1);
  // layer 1
  gemm_bf16_kernel<0,0,0><<<dim3(2, 128), 512, 0, stream>>>(x1, Wt + 2*65536, t1b, xt, nullptr, nullptr);
  gemm_bf16_kernel<0,0,1><<<dim3(2, 128), 512, 0, stream>>>(xt, Wt + 3*65536, p1b, xp, nullptr, idx8);
  scatter_kernel<1><<<dim3(1024, 4), 256, 0, stream>>>(xp, offsets, edgelist, x1, x2);
  // proj (fp32 out) + fused BN stats
  gemm_bf16_kernel<1,1,0><<<dim3(2, 128), 512, 0, stream>>>(x2, Wt + 4*65536, pb, y, bnsum, nullptr);

  final_kernel<<<dim3(64, 4, 4), 256, 0, stream>>>(y, feat, bnsum, gam, bet, out);
}